// Round 17
// baseline (189.428 us; speedup 1.0000x reference)
//
#include <hip/hip_runtime.h>
#include <hip/hip_bf16.h>
#include <stdint.h>

typedef __attribute__((ext_vector_type(4))) float f32x4;
typedef __attribute__((ext_vector_type(8))) short short8;

#define NN 4096      // nodes
#define FIN 128
#define FHID 64
#define BATCH 32
#define NJ 2048      // BATCH * FHID

// ---------- helpers ----------
__device__ __forceinline__ unsigned short f2bf(float f) {
  unsigned u = __builtin_bit_cast(unsigned, f);
  u = (u + 0x7FFFu + ((u >> 16) & 1u)) >> 16;   // RNE
  return (unsigned short)u;
}
__device__ __forceinline__ float bf2f(unsigned short h) {
  unsigned u = ((unsigned)h) << 16;
  return __builtin_bit_cast(float, u);
}
__device__ __forceinline__ void gload_lds16(const void* g, void* l) {
  __builtin_amdgcn_global_load_lds(
      (const __attribute__((address_space(1))) unsigned int*)g,
      (__attribute__((address_space(3))) unsigned int*)l, 16, 0, 0);
}

// ---------- K_pre: fused {adj fp32->bf16 convert} + {support^T GEMM} ----------
__global__ __launch_bounds__(256) void k_pre(const float* __restrict__ adj,
                                             unsigned short* __restrict__ adjb,
                                             const float* __restrict__ x,
                                             const float* __restrict__ W1,
                                             unsigned short* __restrict__ St) {
  __shared__ unsigned short W1t[FHID * 136];              // [h][f], pad 136
  __shared__ __align__(16) unsigned short T[FHID * 128];  // [h][m_loc]
  const int tid = threadIdx.x;

  if (blockIdx.x >= 1024) {
    // ---- convert branch: 2048 blocks x 256 thr x 8 float4 ----
    long base = ((long)blockIdx.x - 1024) * 2048 + tid;
    const f32x4* in = (const f32x4*)adj;
    f32x4 v[8];
    #pragma unroll
    for (int it = 0; it < 8; ++it) v[it] = in[base + it * 256];
    #pragma unroll
    for (int it = 0; it < 8; ++it) {
      ushort4 o;
      o.x = f2bf(v[it].x); o.y = f2bf(v[it].y);
      o.z = f2bf(v[it].z); o.w = f2bf(v[it].w);
      *(ushort4*)(adjb + (base + it * 256) * 4) = o;
    }
    return;
  }

  // ---- support branch (1024 blocks) ----
  for (int i = tid; i < FIN * FHID; i += 256) {
    int f = i >> 6, h = i & 63;
    W1t[h * 136 + f] = f2bf(W1[i]);
  }
  __syncthreads();

  const int bb = blockIdx.x >> 5;
  const int m0 = (blockIdx.x & 31) * 128;
  const int lane = tid & 63, wv = tid >> 6;
  const int fr = lane & 15, fq = lane >> 4;

  short8 bfr[4][4];
  #pragma unroll
  for (int ni = 0; ni < 4; ++ni)
    #pragma unroll
    for (int ks = 0; ks < 4; ++ks)
      bfr[ni][ks] = *(const short8*)&W1t[(ni * 16 + fr) * 136 + ks * 32 + fq * 8];

  const float* xr0 = x + ((size_t)bb * NN + m0 + wv * 32 + fr) * FIN;
  const float* xr1 = xr0 + (size_t)16 * FIN;

  f32x4 z = {0.f, 0.f, 0.f, 0.f};
  f32x4 acc[2][4];
  #pragma unroll
  for (int mf = 0; mf < 2; ++mf)
    #pragma unroll
    for (int ni = 0; ni < 4; ++ni) acc[mf][ni] = z;

  #pragma unroll
  for (int ks = 0; ks < 4; ++ks) {
    #pragma unroll
    for (int mf = 0; mf < 2; ++mf) {
      const float* src = (mf ? xr1 : xr0) + ks * 32 + fq * 8;
      f32x4 lo = *(const f32x4*)src;
      f32x4 hi = *(const f32x4*)(src + 4);
      short8 a;
      #pragma unroll
      for (int j = 0; j < 4; ++j) { a[j] = (short)f2bf(lo[j]); a[4 + j] = (short)f2bf(hi[j]); }
      #pragma unroll
      for (int ni = 0; ni < 4; ++ni)
        acc[mf][ni] = __builtin_amdgcn_mfma_f32_16x16x32_bf16(a, bfr[ni][ks], acc[mf][ni], 0, 0, 0);
    }
  }

  const int cr = (lane >> 4) * 4, cc = lane & 15;
  #pragma unroll
  for (int mf = 0; mf < 2; ++mf)
    #pragma unroll
    for (int ni = 0; ni < 4; ++ni) {
      ushort4 o;
      o.x = f2bf(acc[mf][ni][0]); o.y = f2bf(acc[mf][ni][1]);
      o.z = f2bf(acc[mf][ni][2]); o.w = f2bf(acc[mf][ni][3]);
      *(ushort4*)&T[(ni * 16 + cc) * 128 + wv * 32 + mf * 16 + cr] = o;
    }
  __syncthreads();
  for (int u = tid; u < FHID * 16; u += 256) {
    int row = u >> 4, ch = u & 15;
    *(short8*)(St + (size_t)(bb * FHID + row) * NN + m0 + ch * 8) =
        *(const short8*)&T[row * 128 + ch * 8];
  }
}

// ---------- K2: fused GEMM + bias + relu + row-weighted aggregation ----------
// Geometry: BM=256 x BN=128, BK=64, 8 waves 4M x 2N, per-wave 64x64.
// A: LDS dbuf 64 KB via global_load_lds (XOR-swizzle, pre-swizzled source).
// B: GLOBAL -> REGISTERS directly (L2/L3-resident panel; 8 short8/wave/tile,
//    double-buffered bvE/bvO, prefetched 1 tile ahead) -- no Bs in LDS.
// LDS traffic/tile: 64 KB reads + 32 KB writes (< MFMA floor -> MFMA-bound).
// Schedule: race-safe 2-phase (R15 skeleton), A stages {A10,A11}(t+1)@PhA,
// {A00,A01}(t+2)@PhB. Uniform VMW(12) after each phase's issues gives STRICT
// guarantees: drains B8(t) before PhA(t) MFMA; drains each staged A region
// one full barrier interval before its read. Prologue VMW(2); tails 12/10/0.
#define VMW(N)  asm volatile("s_waitcnt vmcnt(" #N ")" ::: "memory")
#define LGKM0   asm volatile("s_waitcnt lgkmcnt(0)" ::: "memory")
#define BAR     __builtin_amdgcn_s_barrier()

__global__ __launch_bounds__(512, 1) void k_gemm(const unsigned short* __restrict__ A,
                                                 const unsigned short* __restrict__ Bt,
                                                 const float* __restrict__ b1,
                                                 const float* __restrict__ adj,
                                                 const int* __restrict__ q_ids,
                                                 float* __restrict__ partial) {
  __shared__ __align__(16) unsigned short As[2 * 16384];  // A: 256x64 dbuf, 64 KB
  __shared__ float adjw[2][256];                          // 2 KB (epilogue)
  __shared__ float red[8][64];                            // 2 KB (epilogue)

  const int tid  = threadIdx.x;
  const int lane = tid & 63;
  const int wv   = tid >> 6;
  const int wm   = wv >> 1;          // 0..3 (M)
  const int wn   = wv & 1;           // 0..1 (N)
  const int bm   = blockIdx.x * 256;
  const int bn   = blockIdx.y * 128;
  const int fr   = lane & 15;
  const int fq   = lane >> 4;

  // A fragment LDS ushort offsets (buffer-relative)
  int offA[2][2][2];
  #pragma unroll
  for (int h = 0; h < 2; ++h)
    #pragma unroll
    for (int m2 = 0; m2 < 2; ++m2) {
      int row = wm * 32 + h * 128 + m2 * 16 + fr;
      #pragma unroll
      for (int ks = 0; ks < 2; ++ks)
        offA[h][m2][ks] = row * 64 + ((((ks << 6) + (fq << 4)) ^ ((row & 7) << 4)) >> 1);
    }

  // B global fragment base addresses (per-lane): row j of B^T, k base fq*8+ks*32
  const unsigned short* gBF[4][2];
  #pragma unroll
  for (int j = 0; j < 4; ++j)
    #pragma unroll
    for (int ks = 0; ks < 2; ++ks)
      gBF[j][ks] = Bt + (size_t)(bn + wn * 32 + (j & 1) * 16 + (j >> 1) * 64 + fr) * NN
                   + fq * 8 + ks * 32;

  // A staging addresses (pre-swizzled global source, linear LDS dest)
  const int srow = tid >> 3;
  const int scol = ((((tid & 7) << 4) ^ ((srow & 7) << 4)) >> 1);
  const unsigned short* gA00 = A + (size_t)(bm +   0 + srow) * NN + scol;
  const unsigned short* gA01 = A + (size_t)(bm +  64 + srow) * NN + scol;
  const unsigned short* gA10 = A + (size_t)(bm + 128 + srow) * NN + scol;
  const unsigned short* gA11 = A + (size_t)(bm + 192 + srow) * NN + scol;
  const int ld = tid * 8;

  f32x4 z = {0.f, 0.f, 0.f, 0.f};
  f32x4 acc[4][4];
  #pragma unroll
  for (int i = 0; i < 4; ++i)
    #pragma unroll
    for (int j = 0; j < 4; ++j) acc[i][j] = z;

  short8 av0[2][2], av1[2][2], bvE[4][2], bvO[4][2];

#define RD_AVA(Ac)                                                             \
    _Pragma("unroll") for (int m2 = 0; m2 < 2; ++m2)                           \
    _Pragma("unroll") for (int ks = 0; ks < 2; ++ks)                           \
      av0[m2][ks] = *(const short8*)((Ac) + offA[0][m2][ks]);
#define RD_AVB(Ac)                                                             \
    _Pragma("unroll") for (int m2 = 0; m2 < 2; ++m2)                           \
    _Pragma("unroll") for (int ks = 0; ks < 2; ++ks)                           \
      av1[m2][ks] = *(const short8*)((Ac) + offA[1][m2][ks]);
#define LOAD_B8(DST, KQ)                                                       \
    _Pragma("unroll") for (int j = 0; j < 4; ++j)                              \
    _Pragma("unroll") for (int ks = 0; ks < 2; ++ks)                           \
      DST[j][ks] = *(const short8*)(gBF[j][ks] + (KQ));
#define MFMA8(MP, AV, BV, NP)                                                  \
    __builtin_amdgcn_s_setprio(1);                                             \
    _Pragma("unroll") for (int m2 = 0; m2 < 2; ++m2)                           \
    _Pragma("unroll") for (int n2 = 0; n2 < 2; ++n2)                           \
    _Pragma("unroll") for (int ks = 0; ks < 2; ++ks)                           \
      acc[2 * (MP) + m2][2 * (NP) + n2] = __builtin_amdgcn_mfma_f32_16x16x32_bf16( \
          AV[m2][ks], BV[2 * (NP) + n2][ks], acc[2 * (MP) + m2][2 * (NP) + n2], 0, 0, 0); \
    __builtin_amdgcn_s_setprio(0);

// One K-tile, 2 phases. BVC = B regs for tile t; BVN = B regs to fill (t+1).
// KN1 = (t+1)*64 (B8 + A-second stage); KN2 = (t+2)*64 (A-first stage).
#define TILE(CUR, BVC, BVN, KN1, KN2, DOB8, DOSA, DOSB, VMWA, VMWB) {          \
    const unsigned short* Ac = As + (CUR) * 16384;                             \
    /* PhA */                                                                  \
    RD_AVA(Ac)                                                                 \
    if (DOB8) { LOAD_B8(BVN, KN1) }                                            \
    if (DOSA) {  /* A-second(t+1) -> other buf (read at PhB(t-1)) */           \
      gload_lds16(gA10 + (KN1), As + (1 - (CUR)) * 16384 + 2 * 4096 + ld);     \
      gload_lds16(gA11 + (KN1), As + (1 - (CUR)) * 16384 + 3 * 4096 + ld);     \
    }                                                                          \
    VMWA;                                                                      \
    BAR; LGKM0;                                                                \
    MFMA8(0, av0, BVC, 0)                                                      \
    MFMA8(0, av0, BVC, 1)                                                      \
    /* PhB */                                                                  \
    RD_AVB(Ac)                                                                 \
    if (DOSB) {  /* A-first(t+2) -> cur buf (read at this tile's PhA) */       \
      gload_lds16(gA00 + (KN2), As + (CUR) * 16384 + 0 * 4096 + ld);           \
      gload_lds16(gA01 + (KN2), As + (CUR) * 16384 + 1 * 4096 + ld);           \
    }                                                                          \
    VMWB;                                                                      \
    BAR; LGKM0;                                                                \
    MFMA8(1, av1, BVC, 1)                                                      \
    MFMA8(1, av1, BVC, 0)                                                      \
  }

  // ---- prologue: B8(0)->bvE; A-full(t0)->buf0; A-first(t1)->buf1 ----
  LOAD_B8(bvE, 0)
  gload_lds16(gA00,      As + 0 * 4096 + ld);
  gload_lds16(gA01,      As + 1 * 4096 + ld);
  gload_lds16(gA10,      As + 2 * 4096 + ld);
  gload_lds16(gA11,      As + 3 * 4096 + ld);
  gload_lds16(gA00 + 64, As + 16384 + 0 * 4096 + ld);
  gload_lds16(gA01 + 64, As + 16384 + 1 * 4096 + ld);
  VMW(2);                 // drain B8(0) + A-full(t0); keep A-first(t1) in flight
  BAR;                    // => all waves' t0 data visible

  // ---- main loop: 31 macro-iters = tiles 0..61 ----
  int kn = 0;             // t*64 at even tile of the pair
  #pragma unroll 1
  for (int g = 0; g < 31; ++g) {
    TILE(0, bvE, bvO, kn +  64, kn + 128, 1, 1, 1, VMW(12), VMW(12))
    TILE(1, bvO, bvE, kn + 128, kn + 192, 1, 1, 1, VMW(12), VMW(12))
    kn += 128;
  }
  // ---- tile 62 (buf0): B8(63)+A-second(63); no A-first(64) ----
  TILE(0, bvE, bvO, 62 * 64 + 64, 0, 1, 1, 0, VMW(12), VMW(10))
  // ---- tile 63 (buf1): last; drain remaining at PhA ----
  TILE(1, bvO, bvE, 0, 0, 0, 0, 0, VMW(0), (void)0)
#undef RD_AVA
#undef RD_AVB
#undef LOAD_B8
#undef MFMA8
#undef TILE

  // ---- fused epilogue: bias + relu + weight by adj[q_b][row] + reduce ----
  const int b0 = bn >> 6;
  {
    int bsel = tid >> 8;           // 0 or 1
    int rloc = tid & 255;
    adjw[bsel][rloc] = adj[(size_t)q_ids[b0 + bsel] * NN + bm + rloc];
  }
  __syncthreads();

  const int cr = (lane >> 4) * 4;
  const int cc = lane & 15;
  float ps[4];
  #pragma unroll
  for (int ni = 0; ni < 4; ++ni) {
    int colh = wn * 32 + (ni & 1) * 16 + cc;   // h index (col & 63)
    float bias = b1[colh];
    float s = 0.f;
    #pragma unroll
    for (int mi = 0; mi < 4; ++mi) {
      int rowl = wm * 32 + (mi & 1) * 16 + (mi >> 1) * 128 + cr;
      #pragma unroll
      for (int r = 0; r < 4; ++r) {
        float v = acc[mi][ni][r] + bias;
        v = v > 0.f ? v : 0.f;
        s += adjw[ni >> 1][rowl + r] * v;
      }
    }
    ps[ni] = s;
  }
  // reduce across fq groups (lanes differing in bits 4,5)
  #pragma unroll
  for (int ni = 0; ni < 4; ++ni) {
    ps[ni] += __shfl_xor(ps[ni], 16, 64);
    ps[ni] += __shfl_xor(ps[ni], 32, 64);
  }
  if (lane < 16) {
    #pragma unroll
    for (int ni = 0; ni < 4; ++ni)
      red[wm * 2 + wn][ni * 16 + cc] = ps[ni];
  }
  __syncthreads();
  if (tid < 128) {
    int colLocal = tid;
    int wn2 = (colLocal >> 5) & 1;
    int ni2 = ((colLocal >> 6) << 1) | ((colLocal >> 4) & 1);
    int cc2 = colLocal & 15;
    float s = red[0 + wn2][ni2 * 16 + cc2] + red[2 + wn2][ni2 * 16 + cc2]
            + red[4 + wn2][ni2 * 16 + cc2] + red[6 + wn2][ni2 * 16 + cc2];
    partial[(size_t)blockIdx.x * NJ + bn + colLocal] = s;
  }
}

// ---------- K4: out[b][l] = sum_h (sum_rb partial[rb][b*64+h]) * W2[h][l] + b2[l] ----------
__global__ __launch_bounds__(1024) void k_out(const float* __restrict__ partial,
                                              const float* __restrict__ W2,
                                              const float* __restrict__ b2,
                                              float* __restrict__ out) {
  __shared__ float aggs[BATCH * FHID];   // 2048
  int t = threadIdx.x;
  for (int idx = t; idx < BATCH * FHID; idx += 1024) {
    float s = 0.f;
    #pragma unroll
    for (int c = 0; c < 16; ++c) s += partial[c * NJ + idx];
    aggs[idx] = s;
  }
  __syncthreads();
  int b = t >> 5, l = t & 31;
  float o = b2[l];
  #pragma unroll
  for (int h = 0; h < FHID; ++h) o += aggs[b * FHID + h] * W2[h * 32 + l];
  out[b * 32 + l] = o;
}

extern "C" void kernel_launch(void* const* d_in, const int* in_sizes, int n_in,
                              void* d_out, int out_size, void* d_ws, size_t ws_size,
                              hipStream_t stream) {
  const float* x   = (const float*)d_in[0];
  const int*   q   = (const int*)d_in[1];
  const float* adj = (const float*)d_in[2];
  const float* W1  = (const float*)d_in[3];
  const float* b1  = (const float*)d_in[4];
  const float* W2  = (const float*)d_in[5];
  const float* b2  = (const float*)d_in[6];
  float* out = (float*)d_out;

  char* ws = (char*)d_ws;
  unsigned short* adjb   = (unsigned short*)ws;                              // 32 MB
  unsigned short* St     = (unsigned short*)(ws + (size_t)32 * 1024 * 1024); // 16 MB
  float*          partial= (float*)(ws + (size_t)48 * 1024 * 1024);          // 128 KB

  // K_pre: fused convert + support (3072 blocks: 1024 support + 2048 convert)
  k_pre<<<3072, 256, 0, stream>>>(adj, adjb, x, W1, St);
  // K2: fused GEMM + bias/relu + aggregation (B global->reg, A LDS dbuf)
  dim3 g2(NN / 256, NJ / 128);
  k_gemm<<<g2, 512, 0, stream>>>(adjb, St, b1, adj, q, partial);
  // K3: reduce partials + final tiny GEMM
  k_out<<<1, 1024, 0, stream>>>(partial, W2, b2, out);
}

// Round 18
// 94.760 us; speedup vs baseline: 1.9990x; 1.9990x over previous
//
#include <hip/hip_runtime.h>
#include <hip/hip_bf16.h>
#include <stdint.h>

typedef __attribute__((ext_vector_type(4))) float f32x4;
typedef __attribute__((ext_vector_type(8))) short short8;

#define NN 4096      // nodes
#define FIN 128
#define FHID 64
#define BATCH 32
#define NJ 2048      // BATCH * FHID

// ---------- helpers ----------
__device__ __forceinline__ unsigned short f2bf(float f) {
  unsigned u = __builtin_bit_cast(unsigned, f);
  u = (u + 0x7FFFu + ((u >> 16) & 1u)) >> 16;   // RNE
  return (unsigned short)u;
}
__device__ __forceinline__ float bf2f(unsigned short h) {
  unsigned u = ((unsigned)h) << 16;
  return __builtin_bit_cast(float, u);
}
__device__ __forceinline__ void gload_lds16(const void* g, void* l) {
  __builtin_amdgcn_global_load_lds(
      (const __attribute__((address_space(1))) unsigned int*)g,
      (__attribute__((address_space(3))) unsigned int*)l, 16, 0, 0);
}

// ---------- K_pre: fused {adj fp32->bf16 convert} + {support^T GEMM} ----------
__global__ __launch_bounds__(256) void k_pre(const float* __restrict__ adj,
                                             unsigned short* __restrict__ adjb,
                                             const float* __restrict__ x,
                                             const float* __restrict__ W1,
                                             unsigned short* __restrict__ St) {
  __shared__ unsigned short W1t[FHID * 136];              // [h][f], pad 136
  __shared__ __align__(16) unsigned short T[FHID * 128];  // [h][m_loc]
  const int tid = threadIdx.x;

  if (blockIdx.x >= 1024) {
    // ---- convert branch: 2048 blocks x 256 thr x 8 float4 ----
    long base = ((long)blockIdx.x - 1024) * 2048 + tid;
    const f32x4* in = (const f32x4*)adj;
    f32x4 v[8];
    #pragma unroll
    for (int it = 0; it < 8; ++it) v[it] = in[base + it * 256];
    #pragma unroll
    for (int it = 0; it < 8; ++it) {
      ushort4 o;
      o.x = f2bf(v[it].x); o.y = f2bf(v[it].y);
      o.z = f2bf(v[it].z); o.w = f2bf(v[it].w);
      *(ushort4*)(adjb + (base + it * 256) * 4) = o;
    }
    return;
  }

  // ---- support branch (1024 blocks) ----
  for (int i = tid; i < FIN * FHID; i += 256) {
    int f = i >> 6, h = i & 63;
    W1t[h * 136 + f] = f2bf(W1[i]);
  }
  __syncthreads();

  const int bb = blockIdx.x >> 5;
  const int m0 = (blockIdx.x & 31) * 128;
  const int lane = tid & 63, wv = tid >> 6;
  const int fr = lane & 15, fq = lane >> 4;

  short8 bfr[4][4];
  #pragma unroll
  for (int ni = 0; ni < 4; ++ni)
    #pragma unroll
    for (int ks = 0; ks < 4; ++ks)
      bfr[ni][ks] = *(const short8*)&W1t[(ni * 16 + fr) * 136 + ks * 32 + fq * 8];

  const float* xr0 = x + ((size_t)bb * NN + m0 + wv * 32 + fr) * FIN;
  const float* xr1 = xr0 + (size_t)16 * FIN;

  f32x4 z = {0.f, 0.f, 0.f, 0.f};
  f32x4 acc[2][4];
  #pragma unroll
  for (int mf = 0; mf < 2; ++mf)
    #pragma unroll
    for (int ni = 0; ni < 4; ++ni) acc[mf][ni] = z;

  #pragma unroll
  for (int ks = 0; ks < 4; ++ks) {
    #pragma unroll
    for (int mf = 0; mf < 2; ++mf) {
      const float* src = (mf ? xr1 : xr0) + ks * 32 + fq * 8;
      f32x4 lo = *(const f32x4*)src;
      f32x4 hi = *(const f32x4*)(src + 4);
      short8 a;
      #pragma unroll
      for (int j = 0; j < 4; ++j) { a[j] = (short)f2bf(lo[j]); a[4 + j] = (short)f2bf(hi[j]); }
      #pragma unroll
      for (int ni = 0; ni < 4; ++ni)
        acc[mf][ni] = __builtin_amdgcn_mfma_f32_16x16x32_bf16(a, bfr[ni][ks], acc[mf][ni], 0, 0, 0);
    }
  }

  const int cr = (lane >> 4) * 4, cc = lane & 15;
  #pragma unroll
  for (int mf = 0; mf < 2; ++mf)
    #pragma unroll
    for (int ni = 0; ni < 4; ++ni) {
      ushort4 o;
      o.x = f2bf(acc[mf][ni][0]); o.y = f2bf(acc[mf][ni][1]);
      o.z = f2bf(acc[mf][ni][2]); o.w = f2bf(acc[mf][ni][3]);
      *(ushort4*)&T[(ni * 16 + cc) * 128 + wv * 32 + mf * 16 + cr] = o;
    }
  __syncthreads();
  for (int u = tid; u < FHID * 16; u += 256) {
    int row = u >> 4, ch = u & 15;
    *(short8*)(St + (size_t)(bb * FHID + row) * NN + m0 + ch * 8) =
        *(const short8*)&T[row * 128 + ch * 8];
  }
}

// ---------- K2: fused GEMM + bias + relu + row-weighted aggregation ----------
// Geometry: BM=256 x BN=128, BK=64, 8 waves 4M x 2N, per-wave 64x64,
// dbuf LDS 96 KB, XOR-swizzle via pre-swizzled global source.
// Schedule: 2 phases/K-tile with RACE-SAFE staging: every staged region is
// written one full barrier interval AFTER its last ds_read.
//   PhA(t): read A-h0,B0,B1; VMW(6); stage second(t+1)={A10,A11}->other buf
//           (read at t-1-PhB, barrier since); BAR; LGKM0; MFMA Q(0,0)+Q(0,1).
//   PhB(t): read A-h1; VMW(6); stage first(t+2)={A00,A01,B0,B1}->cur buf
//           (read at t-PhA, barrier since); BAR; LGKM0; MFMA Q(1,1)+Q(1,0).
// FIFO (VMW before stages): steady outstanding 10/8 -> VMW(6) drains exactly
// the batch this phase reads. Prologue: t0(6)+first(t1)(4), VMW(4).
// Tail: t62 {VMW6,VMW6,DOSB=0}; t63 {VMW2,VMW0}.
#define VMW(N)  asm volatile("s_waitcnt vmcnt(" #N ")" ::: "memory")
#define LGKM0   asm volatile("s_waitcnt lgkmcnt(0)" ::: "memory")
#define BAR     __builtin_amdgcn_s_barrier()

__global__ __launch_bounds__(512, 1) void k_gemm(const unsigned short* __restrict__ A,
                                                 const unsigned short* __restrict__ Bt,
                                                 const float* __restrict__ b1,
                                                 const float* __restrict__ adj,
                                                 const int* __restrict__ q_ids,
                                                 float* __restrict__ partial) {
  __shared__ __align__(16) unsigned short As[2 * 16384];  // A: 256x64 dbuf, 64 KB
  __shared__ __align__(16) unsigned short Bs[2 * 8192];   // B: 128x64 dbuf, 32 KB
  __shared__ float adjw[2][256];                          // 2 KB (epilogue)
  __shared__ float red[8][64];                            // 2 KB (epilogue)

  const int tid  = threadIdx.x;
  const int lane = tid & 63;
  const int wv   = tid >> 6;
  const int wm   = wv >> 1;          // 0..3 (M)
  const int wn   = wv & 1;           // 0..1 (N)
  const int bm   = blockIdx.x * 256;
  const int bn   = blockIdx.y * 128;
  const int fr   = lane & 15;
  const int fq   = lane >> 4;

  // fragment LDS ushort offsets (buffer-relative)
  int offA[2][2][2], offB[4][2];
  #pragma unroll
  for (int h = 0; h < 2; ++h)
    #pragma unroll
    for (int m2 = 0; m2 < 2; ++m2) {
      int row = wm * 32 + h * 128 + m2 * 16 + fr;
      #pragma unroll
      for (int ks = 0; ks < 2; ++ks)
        offA[h][m2][ks] = row * 64 + ((((ks << 6) + (fq << 4)) ^ ((row & 7) << 4)) >> 1);
    }
  #pragma unroll
  for (int ni = 0; ni < 4; ++ni) {
    int row = wn * 32 + (ni & 1) * 16 + (ni >> 1) * 64 + fr;
    #pragma unroll
    for (int ks = 0; ks < 2; ++ks)
      offB[ni][ks] = row * 64 + ((((ks << 6) + (fq << 4)) ^ ((row & 7) << 4)) >> 1);
  }

  // staging addresses (pre-swizzled global source, linear LDS dest)
  const int srow = tid >> 3;
  const int scol = ((((tid & 7) << 4) ^ ((srow & 7) << 4)) >> 1);
  const unsigned short* gA00 = A + (size_t)(bm +   0 + srow) * NN + scol;
  const unsigned short* gA01 = A + (size_t)(bm +  64 + srow) * NN + scol;
  const unsigned short* gA10 = A + (size_t)(bm + 128 + srow) * NN + scol;
  const unsigned short* gA11 = A + (size_t)(bm + 192 + srow) * NN + scol;
  const unsigned short* gB0  = Bt + (size_t)(bn +  0 + srow) * NN + scol;
  const unsigned short* gB1  = Bt + (size_t)(bn + 64 + srow) * NN + scol;
  const int ld = tid * 8;

  f32x4 z = {0.f, 0.f, 0.f, 0.f};
  f32x4 acc[4][4];
  #pragma unroll
  for (int i = 0; i < 4; ++i)
    #pragma unroll
    for (int j = 0; j < 4; ++j) acc[i][j] = z;

  short8 av0[2][2], av1[2][2], bv0[2][2], bv1[2][2];

#define RD_AVA(Ac)                                                             \
    _Pragma("unroll") for (int m2 = 0; m2 < 2; ++m2)                           \
    _Pragma("unroll") for (int ks = 0; ks < 2; ++ks)                           \
      av0[m2][ks] = *(const short8*)((Ac) + offA[0][m2][ks]);
#define RD_AVB(Ac)                                                             \
    _Pragma("unroll") for (int m2 = 0; m2 < 2; ++m2)                           \
    _Pragma("unroll") for (int ks = 0; ks < 2; ++ks)                           \
      av1[m2][ks] = *(const short8*)((Ac) + offA[1][m2][ks]);
#define RD_BV(DST, Bb, P)                                                      \
    _Pragma("unroll") for (int n2 = 0; n2 < 2; ++n2)                           \
    _Pragma("unroll") for (int ks = 0; ks < 2; ++ks)                           \
      DST[n2][ks] = *(const short8*)((Bb) + offB[2 * (P) + n2][ks]);
#define MFMA8(MP, AV, BV, NP)                                                  \
    __builtin_amdgcn_s_setprio(1);                                             \
    _Pragma("unroll") for (int m2 = 0; m2 < 2; ++m2)                           \
    _Pragma("unroll") for (int n2 = 0; n2 < 2; ++n2)                           \
    _Pragma("unroll") for (int ks = 0; ks < 2; ++ks)                           \
      acc[2 * (MP) + m2][2 * (NP) + n2] = __builtin_amdgcn_mfma_f32_16x16x32_bf16( \
          AV[m2][ks], BV[n2][ks], acc[2 * (MP) + m2][2 * (NP) + n2], 0, 0, 0); \
    __builtin_amdgcn_s_setprio(0);

// Race-safe 2-phase tile. KOA = k-offset of second-batch(t+1);
// KOB = k-offset of first-batch(t+2).
#define TILE(CUR, KOA, KOB, DOSA, DOSB, VMWA, VMWB) {                          \
    const unsigned short* Ac = As + (CUR) * 16384;                             \
    const unsigned short* Bc = Bs + (CUR) * 8192;                              \
    /* PhA */                                                                  \
    RD_AVA(Ac)                                                                 \
    RD_BV(bv0, Bc, 0)                                                          \
    RD_BV(bv1, Bc, 1)                                                          \
    VMWA;                                                                      \
    if (DOSA) {  /* second(t+1) -> other buf: regions read at t-1-PhB */       \
      gload_lds16(gA10 + (KOA), As + (1 - (CUR)) * 16384 + 2 * 4096 + ld);     \
      gload_lds16(gA11 + (KOA), As + (1 - (CUR)) * 16384 + 3 * 4096 + ld);     \
    }                                                                          \
    BAR; LGKM0;                                                                \
    MFMA8(0, av0, bv0, 0)                                                      \
    MFMA8(0, av0, bv1, 1)                                                      \
    /* PhB */                                                                  \
    RD_AVB(Ac)                                                                 \
    VMWB;                                                                      \
    if (DOSB) {  /* first(t+2) -> cur buf: regions read at this tile's PhA */  \
      gload_lds16(gA00 + (KOB), As + (CUR) * 16384 + 0 * 4096 + ld);           \
      gload_lds16(gA01 + (KOB), As + (CUR) * 16384 + 1 * 4096 + ld);           \
      gload_lds16(gB0  + (KOB), Bs + (CUR) * 8192 + 0 * 4096 + ld);            \
      gload_lds16(gB1  + (KOB), Bs + (CUR) * 8192 + 1 * 4096 + ld);            \
    }                                                                          \
    BAR; LGKM0;                                                                \
    MFMA8(1, av1, bv1, 1)                                                      \
    MFMA8(1, av1, bv0, 0)                                                      \
  }

  // ---- prologue: t0 full -> buf0 (6), first(t1) -> buf1 (4) ----
  gload_lds16(gA00,      As + 0 * 4096 + ld);
  gload_lds16(gA01,      As + 1 * 4096 + ld);
  gload_lds16(gB0,       Bs + 0 * 4096 + ld);
  gload_lds16(gB1,       Bs + 1 * 4096 + ld);
  gload_lds16(gA10,      As + 2 * 4096 + ld);
  gload_lds16(gA11,      As + 3 * 4096 + ld);
  gload_lds16(gA00 + 64, As + 16384 + 0 * 4096 + ld);
  gload_lds16(gA01 + 64, As + 16384 + 1 * 4096 + ld);
  gload_lds16(gB0  + 64, Bs + 8192 + 0 * 4096 + ld);
  gload_lds16(gB1  + 64, Bs + 8192 + 1 * 4096 + ld);
  VMW(4);                 // t0's 6 loads drained; first(t1) in flight
  BAR;                    // => all waves' t0 data visible

  // ---- main loop: 31 macro-iters = tiles 0..61 ----
  int koa = 64;           // k-offset of second(t+1) at even tile
  int kob = 128;          // k-offset of first(t+2) at even tile
  #pragma unroll 1
  for (int g = 0; g < 31; ++g) {
    TILE(0, koa,      kob,      1, 1, VMW(6), VMW(6))
    TILE(1, koa + 64, kob + 64, 1, 1, VMW(6), VMW(6))
    koa += 128; kob += 128;
  }
  // ---- tile 62 (buf0): stage second(63) only ----
  TILE(0, 63 * 64, 0, 1, 0, VMW(6), VMW(6))
  // ---- tile 63 (buf1): last, no staging ----
  TILE(1, 0, 0, 0, 0, VMW(2), VMW(0))
#undef RD_AVA
#undef RD_AVB
#undef RD_BV
#undef MFMA8
#undef TILE

  // ---- fused epilogue: bias + relu + weight by adj[q_b][row] + reduce ----
  const int b0 = bn >> 6;
  {
    int bsel = tid >> 8;           // 0 or 1
    int rloc = tid & 255;
    adjw[bsel][rloc] = adj[(size_t)q_ids[b0 + bsel] * NN + bm + rloc];
  }
  __syncthreads();

  const int cr = (lane >> 4) * 4;
  const int cc = lane & 15;
  float ps[4];
  #pragma unroll
  for (int ni = 0; ni < 4; ++ni) {
    int colh = wn * 32 + (ni & 1) * 16 + cc;   // h index (col & 63)
    float bias = b1[colh];
    float s = 0.f;
    #pragma unroll
    for (int mi = 0; mi < 4; ++mi) {
      int rowl = wm * 32 + (mi & 1) * 16 + (mi >> 1) * 128 + cr;
      #pragma unroll
      for (int r = 0; r < 4; ++r) {
        float v = acc[mi][ni][r] + bias;
        v = v > 0.f ? v : 0.f;
        s += adjw[ni >> 1][rowl + r] * v;
      }
    }
    ps[ni] = s;
  }
  // reduce across fq groups (lanes differing in bits 4,5)
  #pragma unroll
  for (int ni = 0; ni < 4; ++ni) {
    ps[ni] += __shfl_xor(ps[ni], 16, 64);
    ps[ni] += __shfl_xor(ps[ni], 32, 64);
  }
  if (lane < 16) {
    #pragma unroll
    for (int ni = 0; ni < 4; ++ni)
      red[wm * 2 + wn][ni * 16 + cc] = ps[ni];
  }
  __syncthreads();
  if (tid < 128) {
    int colLocal = tid;
    int wn2 = (colLocal >> 5) & 1;
    int ni2 = ((colLocal >> 6) << 1) | ((colLocal >> 4) & 1);
    int cc2 = colLocal & 15;
    float s = red[0 + wn2][ni2 * 16 + cc2] + red[2 + wn2][ni2 * 16 + cc2]
            + red[4 + wn2][ni2 * 16 + cc2] + red[6 + wn2][ni2 * 16 + cc2];
    partial[(size_t)blockIdx.x * NJ + bn + colLocal] = s;
  }
}

// ---------- K4: out[b][l] = sum_h (sum_rb partial[rb][b*64+h]) * W2[h][l] + b2[l] ----------
__global__ __launch_bounds__(1024) void k_out(const float* __restrict__ partial,
                                              const float* __restrict__ W2,
                                              const float* __restrict__ b2,
                                              float* __restrict__ out) {
  __shared__ float aggs[BATCH * FHID];   // 2048
  int t = threadIdx.x;
  for (int idx = t; idx < BATCH * FHID; idx += 1024) {
    float s = 0.f;
    #pragma unroll
    for (int c = 0; c < 16; ++c) s += partial[c * NJ + idx];
    aggs[idx] = s;
  }
  __syncthreads();
  int b = t >> 5, l = t & 31;
  float o = b2[l];
  #pragma unroll
  for (int h = 0; h < FHID; ++h) o += aggs[b * FHID + h] * W2[h * 32 + l];
  out[b * 32 + l] = o;
}

extern "C" void kernel_launch(void* const* d_in, const int* in_sizes, int n_in,
                              void* d_out, int out_size, void* d_ws, size_t ws_size,
                              hipStream_t stream) {
  const float* x   = (const float*)d_in[0];
  const int*   q   = (const int*)d_in[1];
  const float* adj = (const float*)d_in[2];
  const float* W1  = (const float*)d_in[3];
  const float* b1  = (const float*)d_in[4];
  const float* W2  = (const float*)d_in[5];
  const float* b2  = (const float*)d_in[6];
  float* out = (float*)d_out;

  char* ws = (char*)d_ws;
  unsigned short* adjb   = (unsigned short*)ws;                              // 32 MB
  unsigned short* St     = (unsigned short*)(ws + (size_t)32 * 1024 * 1024); // 16 MB
  float*          partial= (float*)(ws + (size_t)48 * 1024 * 1024);          // 128 KB

  // K_pre: fused convert + support (3072 blocks: 1024 support + 2048 convert)
  k_pre<<<3072, 256, 0, stream>>>(adj, adjb, x, W1, St);
  // K2: fused GEMM + bias/relu + aggregation (race-safe 2-phase tiles)
  dim3 g2(NN / 256, NJ / 128);
  k_gemm<<<g2, 512, 0, stream>>>(adjb, St, b1, adj, q, partial);
  // K3: reduce partials + final tiny GEMM
  k_out<<<1, 1024, 0, stream>>>(partial, W2, b2, out);
}